// Round 5
// baseline (271.806 us; speedup 1.0000x reference)
//
#include <hip/hip_runtime.h>
#include <hip/hip_bf16.h>

#define NH  12
#define HD  64
#define DIM 768
#define SEQ 2048
#define NB  4
#define MM  (NB*SEQ)   // 8192 rows

typedef short    v8s  __attribute__((ext_vector_type(8)));   // 8 x bf16 (4 VGPRs)
typedef float    v4f  __attribute__((ext_vector_type(4)));
typedef float    v16f __attribute__((ext_vector_type(16)));
typedef unsigned v4u  __attribute__((ext_vector_type(4)));

#if __has_builtin(__builtin_amdgcn_exp2f)
#define EXP2(x) __builtin_amdgcn_exp2f(x)
#else
#define EXP2(x) __builtin_exp2f(x)
#endif

// round-to-nearest-even f32 -> bf16
static __device__ __forceinline__ unsigned short f2b(float f) {
    unsigned int u = __float_as_uint(f);
    return (unsigned short)((u + 0x7FFFu + ((u >> 16) & 1u)) >> 16);
}
// pack two f32 -> (bf16 lo | bf16 hi<<16), round-ties-away: 2 add + 1 perm
static __device__ __forceinline__ unsigned pk2bf(float lo, float hi) {
    return __builtin_amdgcn_perm(__float_as_uint(hi) + 0x8000u,
                                 __float_as_uint(lo) + 0x8000u, 0x07060302u);
}
// async global->LDS DMA, 16B/lane; LDS base wave-uniform, writes base+lane*16
static __device__ __forceinline__ void g2l16(const unsigned short* g, unsigned short* l) {
    __builtin_amdgcn_global_load_lds(
        (const __attribute__((address_space(1))) void*)g,
        (__attribute__((address_space(3))) void*)l, 16, 0, 0);
}

__global__ void cast_f32_bf16(const float* __restrict__ in,
                              unsigned short* __restrict__ out, int n4) {
    int i = blockIdx.x * blockDim.x + threadIdx.x;
    if (i < n4) {
        float4 v = reinterpret_cast<const float4*>(in)[i];
        ushort4 o;
        o.x = f2b(v.x); o.y = f2b(v.y); o.z = f2b(v.z); o.w = f2b(v.w);
        reinterpret_cast<ushort4*>(out)[i] = o;
    }
}

__global__ void cast4_f32_bf16(const float* __restrict__ i0, const float* __restrict__ i1,
                               const float* __restrict__ i2, const float* __restrict__ i3,
                               unsigned short* __restrict__ o0, unsigned short* __restrict__ o1,
                               unsigned short* __restrict__ o2, unsigned short* __restrict__ o3,
                               int n4) {
    int i = blockIdx.x * blockDim.x + threadIdx.x;
    if (i >= n4) return;
    const float* in; unsigned short* out;
    switch (blockIdx.y) {
        case 0: in = i0; out = o0; break;
        case 1: in = i1; out = o1; break;
        case 2: in = i2; out = o2; break;
        default: in = i3; out = o3; break;
    }
    float4 v = reinterpret_cast<const float4*>(in)[i];
    ushort4 o;
    o.x = f2b(v.x); o.y = f2b(v.y); o.z = f2b(v.z); o.w = f2b(v.w);
    reinterpret_cast<ushort4*>(out)[i] = o;
}

// 128x128-tile GEMM core (16x16x32), global_load_lds staging, XOR-swizzled LDS.
static __device__ __forceinline__ void gemm_core_128(
    const unsigned short* __restrict__ A,
    const unsigned short* __restrict__ W,
    int m0, int n0l,
    unsigned short* As, unsigned short* Bs,
    v4f acc[4][4])
{
    const int tid  = threadIdx.x;
    const int w    = tid >> 6, lane = tid & 63;
    const int quad = lane >> 4, l16 = lane & 15;
    const int wm   = w & 1,  wn = w >> 1;
    const int lane8 = lane >> 3, sc = lane & 7;

    #pragma unroll
    for (int i = 0; i < 4; ++i)
        #pragma unroll
        for (int j = 0; j < 4; ++j)
            acc[i][j] = v4f{0.f, 0.f, 0.f, 0.f};

    for (int kb = 0; kb < DIM; kb += 64) {
        __syncthreads();
        #pragma unroll
        for (int t = 0; t < 4; ++t) {
            int r8 = w * 32 + t * 8;
            int r  = r8 + lane8;
            int gch = sc ^ (r & 7);
            g2l16(&A[(size_t)(m0  + r) * DIM + kb + gch * 8], &As[r8 * 64]);
            g2l16(&W[(size_t)(n0l + r) * DIM + kb + gch * 8], &Bs[r8 * 64]);
        }
        __syncthreads();
        #pragma unroll
        for (int kk = 0; kk < 64; kk += 32) {
            v8s a[4], b[4];
            int chb = kk >> 3;
            #pragma unroll
            for (int i = 0; i < 4; ++i) {
                int m = wm * 64 + i * 16 + l16;
                a[i] = *reinterpret_cast<const v8s*>(
                    &As[m * 64 + (((chb + quad) ^ (m & 7)) << 3)]);
                int n = wn * 64 + i * 16 + l16;
                b[i] = *reinterpret_cast<const v8s*>(
                    &Bs[n * 64 + (((chb + quad) ^ (n & 7)) << 3)]);
            }
            #pragma unroll
            for (int i = 0; i < 4; ++i)
                #pragma unroll
                for (int j = 0; j < 4; ++j)
                    acc[i][j] = __builtin_amdgcn_mfma_f32_16x16x32_bf16(a[i], b[j], acc[i][j], 0, 0, 0);
        }
    }
}

// Fused QKV projection. grid (64, 18): y/6 selects {Q,K,V}.
__global__ __launch_bounds__(256) void gemm_qkv(
    const unsigned short* __restrict__ A,
    const unsigned short* __restrict__ Wq,
    const unsigned short* __restrict__ Wk,
    const unsigned short* __restrict__ Wv,
    const float* __restrict__ bq,
    const float* __restrict__ bk,
    const float* __restrict__ bvp,
    unsigned short* __restrict__ Qb,
    unsigned short* __restrict__ Kb,
    unsigned short* __restrict__ Vtb)
{
    __shared__ __align__(16) unsigned short As[128 * 64];
    __shared__ __align__(16) unsigned short Bs[128 * 64];

    const int m0   = blockIdx.x * 128;
    const int by   = blockIdx.y;
    const int wsel = by / 6;
    const int n0l  = (by % 6) * 128;
    const unsigned short* W    = (wsel == 0) ? Wq : (wsel == 1) ? Wk : Wv;
    const float*          bias = (wsel == 0) ? bq : (wsel == 1) ? bk : bvp;
    unsigned short*       out  = (wsel == 0) ? Qb : (wsel == 1) ? Kb : Vtb;
    const float scale = (wsel == 0) ? 0.1803368801f : 1.0f;  // 0.125*log2(e) for Q

    v4f acc[4][4];
    gemm_core_128(A, W, m0, n0l, As, Bs, acc);

    const int tid  = threadIdx.x;
    const int w    = tid >> 6, lane = tid & 63;
    const int quad = lane >> 4, l16 = lane & 15;
    const int wm   = w & 1,  wn = w >> 1;

    #pragma unroll
    for (int i = 0; i < 4; ++i) {
        #pragma unroll
        for (int j = 0; j < 4; ++j) {
            int gnl = n0l + wn * 64 + j * 16 + l16;
            float bias_v = bias[gnl];
            int h = gnl >> 6, hd = gnl & 63;
            if (wsel == 2) {
                int gm0 = m0 + wm * 64 + i * 16 + quad * 4;
                int bb = gm0 >> 11, s0 = gm0 & (SEQ - 1);
                ushort4 pkv;
                pkv.x = f2b(acc[i][j][0] + bias_v);
                pkv.y = f2b(acc[i][j][1] + bias_v);
                pkv.z = f2b(acc[i][j][2] + bias_v);
                pkv.w = f2b(acc[i][j][3] + bias_v);
                *reinterpret_cast<ushort4*>(
                    &out[((size_t)(bb * NH + h) * HD + hd) * SEQ + s0]) = pkv;
            } else {
                #pragma unroll
                for (int r = 0; r < 4; ++r) {
                    int gm = m0 + wm * 64 + i * 16 + quad * 4 + r;
                    int bb = gm >> 11, s = gm & (SEQ - 1);
                    out[((size_t)(bb * NH + h) * SEQ + s) * HD + hd] =
                        f2b((acc[i][j][r] + bias_v) * scale);
                }
            }
        }
    }
}

// Output projection: f32 out. grid (64, 6).
__global__ __launch_bounds__(256) void gemm_o(
    const unsigned short* __restrict__ A,
    const unsigned short* __restrict__ W,
    const float* __restrict__ bias,
    float* __restrict__ out)
{
    __shared__ __align__(16) unsigned short As[128 * 64];
    __shared__ __align__(16) unsigned short Bs[128 * 64];

    const int m0  = blockIdx.x * 128;
    const int n0l = blockIdx.y * 128;

    v4f acc[4][4];
    gemm_core_128(A, W, m0, n0l, As, Bs, acc);

    const int tid  = threadIdx.x;
    const int w    = tid >> 6, lane = tid & 63;
    const int quad = lane >> 4, l16 = lane & 15;
    const int wm   = w & 1,  wn = w >> 1;

    #pragma unroll
    for (int i = 0; i < 4; ++i) {
        #pragma unroll
        for (int j = 0; j < 4; ++j) {
            int gn = n0l + wn * 64 + j * 16 + l16;
            float bias_v = bias[gn];
            #pragma unroll
            for (int r = 0; r < 4; ++r) {
                int gm = m0 + wm * 64 + i * 16 + quad * 4 + r;
                out[(size_t)gm * DIM + gn] = acc[i][j][r] + bias_v;
            }
        }
    }
}

// Transposed flash attention: S^T = mfma(A=K, B=Q) so each lane owns one
// q-column. Softmax is lane-local (li = 1 scalar). P^T B-frags built in
// registers via shfl_xor(32) + cndmask — NO P LDS round-trip. V read direct
// from global (L1-cached, prefetched); only K staged in LDS (dbuf 16KB).
// O^T = mfma(A=V, B=P^T). grid (SEQ/128, NB*NH), 4 waves, 32 q-rows/wave.
__global__ __launch_bounds__(256, 3) void attn(
    const unsigned short* __restrict__ Q,
    const unsigned short* __restrict__ K,
    const unsigned short* __restrict__ Vt,
    unsigned short* __restrict__ ctx)
{
    __shared__ __align__(16) unsigned short Ks[2][64 * 64];   // 16 KB

    const int tid  = threadIdx.x;
    const int w    = tid >> 6, lane = tid & 63;
    const int l31  = lane & 31, half = lane >> 5;
    const int lane8 = lane >> 3, sc = lane & 7;
    const int bh   = blockIdx.y;
    const int b    = bh / NH, h = bh % NH;
    const int q0   = blockIdx.x * 128 + w * 32;

    const unsigned short* Qp = Q  + ((size_t)bh * SEQ + q0) * HD;
    const unsigned short* Kp = K  + (size_t)bh * SEQ * HD;
    const unsigned short* Vp = Vt + (size_t)bh * HD * SEQ;

    // Q B-frag: B[n=q=l31][k = c*16 + half*8 + j] (Q pre-scaled by 0.125*log2e)
    v8s bq[4];
    #pragma unroll
    for (int c = 0; c < 4; ++c)
        bq[c] = *reinterpret_cast<const v8s*>(&Qp[l31 * HD + c * 16 + half * 8]);

    // V A-frags (prefetched): va[hb][c] = Vt[hd = hb*32+l31][key = kb + c*16 + half*8 ..+7]
    v8s va[2][4];
    #pragma unroll
    for (int hb = 0; hb < 2; ++hb)
        #pragma unroll
        for (int c = 0; c < 4; ++c)
            va[hb][c] = *reinterpret_cast<const v8s*>(
                &Vp[(size_t)(hb * 32 + l31) * SEQ + c * 16 + half * 8]);

    v16f o0, o1, Z;
    #pragma unroll
    for (int i = 0; i < 16; ++i) { o0[i] = 0.f; o1[i] = 0.f; Z[i] = 0.f; }
    float li = 0.f;

    // K A-frag LDS offsets: row=l31 (s0) / +2048 elems (s1), chunk=(c*2+half)^(row&7)
    const int rx = l31 & 7;
    int rdoff[4];
    #pragma unroll
    for (int c = 0; c < 4; ++c)
        rdoff[c] = l31 * 64 + (((c * 2 + half) ^ rx) << 3);

    #define STAGE_K(kb_, buf_)                                                       \
        do {                                                                         \
            _Pragma("unroll")                                                        \
            for (int t = 0; t < 2; ++t) {                                            \
                int r8  = (t * 4 + w) * 8;                                           \
                int row = r8 + lane8;                                                \
                int gch = sc ^ (row & 7);                                            \
                g2l16(&Kp[(size_t)((kb_) + row) * HD + gch * 8], &Ks[buf_][r8 * 64]);\
            }                                                                        \
        } while (0)

    STAGE_K(0, 0);

    for (int it = 0; it < SEQ / 64; ++it) {
        const int buf = it & 1;
        const int kb  = it * 64;
        __syncthreads();                        // drains K-DMA(it) + va prefetch
        if (it + 1 < SEQ / 64) STAGE_K(kb + 64, buf ^ 1);

        // S^T[key][q]: s0 = keys kb+0..31 (rows l31), s1 = keys kb+32..63
        v16f s0 = Z, s1 = Z;
        {
            v8s ka00 = *reinterpret_cast<const v8s*>(&Ks[buf][rdoff[0]]);
            v8s ka10 = *reinterpret_cast<const v8s*>(&Ks[buf][rdoff[0] + 2048]);
            s0 = __builtin_amdgcn_mfma_f32_32x32x16_bf16(ka00, bq[0], Z, 0, 0, 0);
            s1 = __builtin_amdgcn_mfma_f32_32x32x16_bf16(ka10, bq[0], Z, 0, 0, 0);
            #pragma unroll
            for (int c = 1; c < 4; ++c) {
                v8s k0 = *reinterpret_cast<const v8s*>(&Ks[buf][rdoff[c]]);
                v8s k1 = *reinterpret_cast<const v8s*>(&Ks[buf][rdoff[c] + 2048]);
                s0 = __builtin_amdgcn_mfma_f32_32x32x16_bf16(k0, bq[c], s0, 0, 0, 0);
                s1 = __builtin_amdgcn_mfma_f32_32x32x16_bf16(k1, bq[c], s1, 0, 0, 0);
            }
        }

        // exp2 + lane-local li + pack pairs. Lane owns keys 8G+4*half+r,
        // G=0..3 from s0 (regs 4G+r), G=4..7 from s1.
        unsigned pk[8][2];
        #pragma unroll
        for (int g = 0; g < 4; ++g) {
            float e0 = EXP2(s0[4*g+0]), e1 = EXP2(s0[4*g+1]);
            float e2 = EXP2(s0[4*g+2]), e3 = EXP2(s0[4*g+3]);
            li += (e0 + e1) + (e2 + e3);
            pk[g][0] = pk2bf(e0, e1);
            pk[g][1] = pk2bf(e2, e3);
            float f0 = EXP2(s1[4*g+0]), f1 = EXP2(s1[4*g+1]);
            float f2 = EXP2(s1[4*g+2]), f3 = EXP2(s1[4*g+3]);
            li += (f0 + f1) + (f2 + f3);
            pk[4+g][0] = pk2bf(f0, f1);
            pk[4+g][1] = pk2bf(f2, f3);
        }

        // Build P^T B-frags (n=q, k=key block 16cp..16cp+15) + PV MFMAs.
        // frag elem j: key = 16cp + 8*half + j  -> own group (2cp+half) half,
        // partner (lane^32) supplies the other 4-key sub-block.
        #pragma unroll
        for (int cp = 0; cp < 4; ++cp) {
            unsigned a0 = pk[2*cp][0],   a1 = pk[2*cp][1];
            unsigned b0 = pk[2*cp+1][0], b1 = pk[2*cp+1][1];
            unsigned xa0 = __shfl_xor(a0, 32), xa1 = __shfl_xor(a1, 32);
            unsigned xb0 = __shfl_xor(b0, 32), xb1 = __shfl_xor(b1, 32);
            v4u fw;
            fw.x = half ? xb0 : a0;
            fw.y = half ? xb1 : a1;
            fw.z = half ? b0  : xa0;
            fw.w = half ? b1  : xa1;
            v8s pf = __builtin_bit_cast(v8s, fw);
            o0 = __builtin_amdgcn_mfma_f32_32x32x16_bf16(va[0][cp], pf, o0, 0, 0, 0);
            o1 = __builtin_amdgcn_mfma_f32_32x32x16_bf16(va[1][cp], pf, o1, 0, 0, 0);
        }

        // prefetch next V tile into va (overlaps with next QK^T + softmax)
        if (it + 1 < SEQ / 64) {
            #pragma unroll
            for (int hb = 0; hb < 2; ++hb)
                #pragma unroll
                for (int c = 0; c < 4; ++c)
                    va[hb][c] = *reinterpret_cast<const v8s*>(
                        &Vp[(size_t)(hb * 32 + l31) * SEQ + kb + 64 + c * 16 + half * 8]);
        }
    }
    #undef STAGE_K

    // li total = own 32 keys + partner's 32 keys (same q)
    float inv = 1.0f / (li + __shfl_xor(li, 32));

    // O^T: lane holds q = q0+l31; rows hd = (reg&3)+8*(reg>>2)+4*half (+32 for o1)
    const int q = q0 + l31;
    size_t base = ((size_t)(b * SEQ + q)) * DIM + h * HD;
    #pragma unroll
    for (int g = 0; g < 4; ++g) {
        int hd0 = 8 * g + 4 * half;
        uint2 u0, u1;
        u0.x = pk2bf(o0[4*g+0] * inv, o0[4*g+1] * inv);
        u0.y = pk2bf(o0[4*g+2] * inv, o0[4*g+3] * inv);
        u1.x = pk2bf(o1[4*g+0] * inv, o1[4*g+1] * inv);
        u1.y = pk2bf(o1[4*g+2] * inv, o1[4*g+3] * inv);
        *reinterpret_cast<uint2*>(&ctx[base + hd0])      = u0;
        *reinterpret_cast<uint2*>(&ctx[base + 32 + hd0]) = u1;
    }
}

extern "C" void kernel_launch(void* const* d_in, const int* in_sizes, int n_in,
                              void* d_out, int out_size, void* d_ws, size_t ws_size,
                              hipStream_t stream) {
    const float* x  = (const float*)d_in[0];
    const float* qw = (const float*)d_in[1]; const float* qb = (const float*)d_in[2];
    const float* kw = (const float*)d_in[3]; const float* kb = (const float*)d_in[4];
    const float* vw = (const float*)d_in[5]; const float* vb = (const float*)d_in[6];
    const float* ow = (const float*)d_in[7]; const float* ob = (const float*)d_in[8];
    float* out = (float*)d_out;

    char* ws = (char*)d_ws;
    size_t off = 0;
    auto alloc = [&](size_t bytes) -> unsigned short* {
        unsigned short* p = (unsigned short*)(ws + off);
        off += (bytes + 255) & ~(size_t)255;
        return p;
    };
    const size_t XB = (size_t)MM * DIM * 2;
    const size_t WB = (size_t)DIM * DIM * 2;
    const size_t QB = (size_t)NB * NH * SEQ * HD * 2;

    unsigned short* xb  = alloc(XB);
    unsigned short* wqb = alloc(WB);
    unsigned short* wkb = alloc(WB);
    unsigned short* wvb = alloc(WB);
    unsigned short* wob = alloc(WB);
    unsigned short* Qb  = alloc(QB);
    unsigned short* Kb  = alloc(QB);
    unsigned short* Vtb = alloc(QB);
    unsigned short* ctx = alloc(XB);

    const int n4x = MM * DIM / 4;
    const int n4w = DIM * DIM / 4;
    cast_f32_bf16<<<(n4x + 255) / 256, 256, 0, stream>>>(x, xb, n4x);
    cast4_f32_bf16<<<dim3((n4w + 255) / 256, 4), 256, 0, stream>>>(
        qw, kw, vw, ow, wqb, wkb, wvb, wob, n4w);

    gemm_qkv<<<dim3(MM / 128, 18), 256, 0, stream>>>(
        xb, wqb, wkb, wvb, qb, kb, vb, Qb, Kb, Vtb);

    attn<<<dim3(SEQ / 128, NB * NH), 256, 0, stream>>>(Qb, Kb, Vtb, ctx);

    gemm_o<<<dim3(MM / 128, DIM / 128), 256, 0, stream>>>(ctx, wob, ob, out);
}

// Round 6
// 234.088 us; speedup vs baseline: 1.1611x; 1.1611x over previous
//
#include <hip/hip_runtime.h>
#include <hip/hip_bf16.h>

#define NH  12
#define HD  64
#define DIM 768
#define SEQ 2048
#define NB  4
#define MM  (NB*SEQ)   // 8192 rows
#define NKB (SEQ/64)   // 32 key-blocks per head

typedef short    v8s  __attribute__((ext_vector_type(8)));   // 8 x bf16 (4 VGPRs)
typedef float    v4f  __attribute__((ext_vector_type(4)));
typedef float    v16f __attribute__((ext_vector_type(16)));
typedef unsigned v4u  __attribute__((ext_vector_type(4)));

#if __has_builtin(__builtin_amdgcn_exp2f)
#define EXP2(x) __builtin_amdgcn_exp2f(x)
#else
#define EXP2(x) __builtin_exp2f(x)
#endif

// round-to-nearest-even f32 -> bf16
static __device__ __forceinline__ unsigned short f2b(float f) {
    unsigned int u = __float_as_uint(f);
    return (unsigned short)((u + 0x7FFFu + ((u >> 16) & 1u)) >> 16);
}
// pack two f32 -> (bf16 lo | bf16 hi<<16), round-ties-away: 2 add + 1 perm
static __device__ __forceinline__ unsigned pk2bf(float lo, float hi) {
    return __builtin_amdgcn_perm(__float_as_uint(hi) + 0x8000u,
                                 __float_as_uint(lo) + 0x8000u, 0x07060302u);
}
// async global->LDS DMA, 16B/lane; LDS base wave-uniform, writes base+lane*16
static __device__ __forceinline__ void g2l16(const unsigned short* g, unsigned short* l) {
    __builtin_amdgcn_global_load_lds(
        (const __attribute__((address_space(1))) void*)g,
        (__attribute__((address_space(3))) void*)l, 16, 0, 0);
}

__global__ void cast_f32_bf16(const float* __restrict__ in,
                              unsigned short* __restrict__ out, int n4) {
    int i = blockIdx.x * blockDim.x + threadIdx.x;
    if (i < n4) {
        float4 v = reinterpret_cast<const float4*>(in)[i];
        ushort4 o;
        o.x = f2b(v.x); o.y = f2b(v.y); o.z = f2b(v.z); o.w = f2b(v.w);
        reinterpret_cast<ushort4*>(out)[i] = o;
    }
}

__global__ void cast4_f32_bf16(const float* __restrict__ i0, const float* __restrict__ i1,
                               const float* __restrict__ i2, const float* __restrict__ i3,
                               unsigned short* __restrict__ o0, unsigned short* __restrict__ o1,
                               unsigned short* __restrict__ o2, unsigned short* __restrict__ o3,
                               int n4) {
    int i = blockIdx.x * blockDim.x + threadIdx.x;
    if (i >= n4) return;
    const float* in; unsigned short* out;
    switch (blockIdx.y) {
        case 0: in = i0; out = o0; break;
        case 1: in = i1; out = o1; break;
        case 2: in = i2; out = o2; break;
        default: in = i3; out = o3; break;
    }
    float4 v = reinterpret_cast<const float4*>(in)[i];
    ushort4 o;
    o.x = f2b(v.x); o.y = f2b(v.y); o.z = f2b(v.z); o.w = f2b(v.w);
    reinterpret_cast<ushort4*>(out)[i] = o;
}

// 128x128-tile GEMM core (16x16x32), global_load_lds staging, XOR-swizzled LDS.
static __device__ __forceinline__ void gemm_core_128(
    const unsigned short* __restrict__ A,
    const unsigned short* __restrict__ W,
    int m0, int n0l,
    unsigned short* As, unsigned short* Bs,
    v4f acc[4][4])
{
    const int tid  = threadIdx.x;
    const int w    = tid >> 6, lane = tid & 63;
    const int quad = lane >> 4, l16 = lane & 15;
    const int wm   = w & 1,  wn = w >> 1;
    const int lane8 = lane >> 3, sc = lane & 7;

    #pragma unroll
    for (int i = 0; i < 4; ++i)
        #pragma unroll
        for (int j = 0; j < 4; ++j)
            acc[i][j] = v4f{0.f, 0.f, 0.f, 0.f};

    for (int kb = 0; kb < DIM; kb += 64) {
        __syncthreads();
        #pragma unroll
        for (int t = 0; t < 4; ++t) {
            int r8 = w * 32 + t * 8;
            int r  = r8 + lane8;
            int gch = sc ^ (r & 7);
            g2l16(&A[(size_t)(m0  + r) * DIM + kb + gch * 8], &As[r8 * 64]);
            g2l16(&W[(size_t)(n0l + r) * DIM + kb + gch * 8], &Bs[r8 * 64]);
        }
        __syncthreads();
        #pragma unroll
        for (int kk = 0; kk < 64; kk += 32) {
            v8s a[4], b[4];
            int chb = kk >> 3;
            #pragma unroll
            for (int i = 0; i < 4; ++i) {
                int m = wm * 64 + i * 16 + l16;
                a[i] = *reinterpret_cast<const v8s*>(
                    &As[m * 64 + (((chb + quad) ^ (m & 7)) << 3)]);
                int n = wn * 64 + i * 16 + l16;
                b[i] = *reinterpret_cast<const v8s*>(
                    &Bs[n * 64 + (((chb + quad) ^ (n & 7)) << 3)]);
            }
            #pragma unroll
            for (int i = 0; i < 4; ++i)
                #pragma unroll
                for (int j = 0; j < 4; ++j)
                    acc[i][j] = __builtin_amdgcn_mfma_f32_16x16x32_bf16(a[i], b[j], acc[i][j], 0, 0, 0);
        }
    }
}

// Fused QKV projection. grid (64, 18): y/6 selects {Q,K,V}.
// V goes to fragment-native layout Vf[bh][kbi][hb][c][lane][8] so attn's
// PV A-frag load is one coalesced dwordx4 per lane.
__global__ __launch_bounds__(256) void gemm_qkv(
    const unsigned short* __restrict__ A,
    const unsigned short* __restrict__ Wq,
    const unsigned short* __restrict__ Wk,
    const unsigned short* __restrict__ Wv,
    const float* __restrict__ bq,
    const float* __restrict__ bk,
    const float* __restrict__ bvp,
    unsigned short* __restrict__ Qb,
    unsigned short* __restrict__ Kb,
    unsigned short* __restrict__ Vf)
{
    __shared__ __align__(16) unsigned short As[128 * 64];
    __shared__ __align__(16) unsigned short Bs[128 * 64];

    const int m0   = blockIdx.x * 128;
    const int by   = blockIdx.y;
    const int wsel = by / 6;
    const int n0l  = (by % 6) * 128;
    const unsigned short* W    = (wsel == 0) ? Wq : (wsel == 1) ? Wk : Wv;
    const float*          bias = (wsel == 0) ? bq : (wsel == 1) ? bk : bvp;
    const float scale = (wsel == 0) ? 0.1803368801f : 1.0f;  // 0.125*log2(e) for Q

    v4f acc[4][4];
    gemm_core_128(A, W, m0, n0l, As, Bs, acc);

    const int tid  = threadIdx.x;
    const int w    = tid >> 6, lane = tid & 63;
    const int quad = lane >> 4, l16 = lane & 15;
    const int wm   = w & 1,  wn = w >> 1;

    #pragma unroll
    for (int i = 0; i < 4; ++i) {
        #pragma unroll
        for (int j = 0; j < 4; ++j) {
            int gnl = n0l + wn * 64 + j * 16 + l16;
            float bias_v = bias[gnl];
            int h = gnl >> 6, hd = gnl & 63;
            if (wsel == 2) {
                // 4 consecutive keys -> j0..j0+3 of fragment (kbi, hb, c=i)
                int gm0 = m0 + wm * 64 + i * 16 + quad * 4;
                int bb = gm0 >> 11, s0k = gm0 & (SEQ - 1);
                int kbi = s0k >> 6;
                int halfv = quad >> 1, j0 = (quad & 1) * 4;
                int hb = hd >> 5, l31v = hd & 31;
                ushort4 pkv;
                pkv.x = f2b(acc[i][j][0] + bias_v);
                pkv.y = f2b(acc[i][j][1] + bias_v);
                pkv.z = f2b(acc[i][j][2] + bias_v);
                pkv.w = f2b(acc[i][j][3] + bias_v);
                size_t frag = ((size_t)(bb * NH + h) * NKB + kbi) * 8 + hb * 4 + i;
                *reinterpret_cast<ushort4*>(
                    &Vf[frag * 512 + (halfv * 32 + l31v) * 8 + j0]) = pkv;
            } else {
                unsigned short* out = (wsel == 0) ? Qb : Kb;
                #pragma unroll
                for (int r = 0; r < 4; ++r) {
                    int gm = m0 + wm * 64 + i * 16 + quad * 4 + r;
                    int bb = gm >> 11, s = gm & (SEQ - 1);
                    out[((size_t)(bb * NH + h) * SEQ + s) * HD + hd] =
                        f2b((acc[i][j][r] + bias_v) * scale);
                }
            }
        }
    }
}

// Output projection: f32 out. grid (64, 6).
__global__ __launch_bounds__(256) void gemm_o(
    const unsigned short* __restrict__ A,
    const unsigned short* __restrict__ W,
    const float* __restrict__ bias,
    float* __restrict__ out)
{
    __shared__ __align__(16) unsigned short As[128 * 64];
    __shared__ __align__(16) unsigned short Bs[128 * 64];

    const int m0  = blockIdx.x * 128;
    const int n0l = blockIdx.y * 128;

    v4f acc[4][4];
    gemm_core_128(A, W, m0, n0l, As, Bs, acc);

    const int tid  = threadIdx.x;
    const int w    = tid >> 6, lane = tid & 63;
    const int quad = lane >> 4, l16 = lane & 15;
    const int wm   = w & 1,  wn = w >> 1;

    #pragma unroll
    for (int i = 0; i < 4; ++i) {
        #pragma unroll
        for (int j = 0; j < 4; ++j) {
            int gn = n0l + wn * 64 + j * 16 + l16;
            float bias_v = bias[gn];
            #pragma unroll
            for (int r = 0; r < 4; ++r) {
                int gm = m0 + wm * 64 + i * 16 + quad * 4 + r;
                out[(size_t)gm * DIM + gn] = acc[i][j][r] + bias_v;
            }
        }
    }
}

// Transposed flash attention: S^T = mfma(A=K, B=Q), lane owns one q-column,
// softmax lane-local, P^T built in registers (2 shfl_xor(32)/cp), V read as
// coalesced fragment-native global loads (prefetched), K in LDS dbuf (16KB).
__global__ __launch_bounds__(256, 3) void attn(
    const unsigned short* __restrict__ Q,
    const unsigned short* __restrict__ K,
    const unsigned short* __restrict__ Vf,
    unsigned short* __restrict__ ctx)
{
    __shared__ __align__(16) unsigned short Ks[2][64 * 64];   // 16 KB

    const int tid  = threadIdx.x;
    const int w    = tid >> 6, lane = tid & 63;
    const int l31  = lane & 31, half = lane >> 5;
    const int lane8 = lane >> 3, sc = lane & 7;
    const int bh   = blockIdx.y;
    const int b    = bh / NH, h = bh % NH;
    const int q0   = blockIdx.x * 128 + w * 32;

    const unsigned short* Qp = Q  + ((size_t)bh * SEQ + q0) * HD;
    const unsigned short* Kp = K  + (size_t)bh * SEQ * HD;
    // per-head fragment base; frag(it,hb,c) at +((it*8 + hb*4 + c)*512), lane at +lane*8
    const unsigned short* Vh = Vf + (size_t)bh * NKB * 8 * 512 + lane * 8;

    // Q B-frag: B[n=q=l31][k = c*16 + half*8 + j] (Q pre-scaled by 0.125*log2e)
    v8s bq[4];
    #pragma unroll
    for (int c = 0; c < 4; ++c)
        bq[c] = *reinterpret_cast<const v8s*>(&Qp[l31 * HD + c * 16 + half * 8]);

    // V A-frags for tile 0 (coalesced: consecutive lanes -> consecutive 16B)
    v8s va[2][4];
    #pragma unroll
    for (int hb = 0; hb < 2; ++hb)
        #pragma unroll
        for (int c = 0; c < 4; ++c)
            va[hb][c] = *reinterpret_cast<const v8s*>(&Vh[(hb * 4 + c) * 512]);

    v16f o0, o1, Z;
    #pragma unroll
    for (int i = 0; i < 16; ++i) { o0[i] = 0.f; o1[i] = 0.f; Z[i] = 0.f; }
    float li = 0.f;

    // K A-frag LDS offsets: row=l31 (s0) / +2048 elems (s1), chunk=(c*2+half)^(row&7)
    const int rx = l31 & 7;
    int rdoff[4];
    #pragma unroll
    for (int c = 0; c < 4; ++c)
        rdoff[c] = l31 * 64 + (((c * 2 + half) ^ rx) << 3);

    #define STAGE_K(kb_, buf_)                                                       \
        do {                                                                         \
            _Pragma("unroll")                                                        \
            for (int t = 0; t < 2; ++t) {                                            \
                int r8  = (t * 4 + w) * 8;                                           \
                int row = r8 + lane8;                                                \
                int gch = sc ^ (row & 7);                                            \
                g2l16(&Kp[(size_t)((kb_) + row) * HD + gch * 8], &Ks[buf_][r8 * 64]);\
            }                                                                        \
        } while (0)

    STAGE_K(0, 0);

    for (int it = 0; it < NKB; ++it) {
        const int buf = it & 1;
        __syncthreads();                        // drains K-DMA(it)
        if (it + 1 < NKB) STAGE_K((it + 1) * 64, buf ^ 1);

        // S^T[key][q]: s0 = keys 0..31 of tile, s1 = keys 32..63
        v16f s0, s1;
        {
            v8s ka00 = *reinterpret_cast<const v8s*>(&Ks[buf][rdoff[0]]);
            v8s ka10 = *reinterpret_cast<const v8s*>(&Ks[buf][rdoff[0] + 2048]);
            s0 = __builtin_amdgcn_mfma_f32_32x32x16_bf16(ka00, bq[0], Z, 0, 0, 0);
            s1 = __builtin_amdgcn_mfma_f32_32x32x16_bf16(ka10, bq[0], Z, 0, 0, 0);
            #pragma unroll
            for (int c = 1; c < 4; ++c) {
                v8s k0 = *reinterpret_cast<const v8s*>(&Ks[buf][rdoff[c]]);
                v8s k1 = *reinterpret_cast<const v8s*>(&Ks[buf][rdoff[c] + 2048]);
                s0 = __builtin_amdgcn_mfma_f32_32x32x16_bf16(k0, bq[c], s0, 0, 0, 0);
                s1 = __builtin_amdgcn_mfma_f32_32x32x16_bf16(k1, bq[c], s1, 0, 0, 0);
            }
        }

        // exp2 + lane-local li + pack key-pairs
        unsigned pk[8][2];
        #pragma unroll
        for (int g = 0; g < 4; ++g) {
            float e0 = EXP2(s0[4*g+0]), e1 = EXP2(s0[4*g+1]);
            float e2 = EXP2(s0[4*g+2]), e3 = EXP2(s0[4*g+3]);
            li += (e0 + e1) + (e2 + e3);
            pk[g][0] = pk2bf(e0, e1);
            pk[g][1] = pk2bf(e2, e3);
            float f0 = EXP2(s1[4*g+0]), f1 = EXP2(s1[4*g+1]);
            float f2 = EXP2(s1[4*g+2]), f3 = EXP2(s1[4*g+3]);
            li += (f0 + f1) + (f2 + f3);
            pk[4+g][0] = pk2bf(f0, f1);
            pk[4+g][1] = pk2bf(f2, f3);
        }

        // P^T B-frags: partner (lane^32) holds the complementary 4-key blocks.
        // Pre-select so only 2 shuffles per cp are needed.
        #pragma unroll
        for (int cp = 0; cp < 4; ++cp) {
            unsigned a0 = pk[2*cp][0],   a1 = pk[2*cp][1];
            unsigned b0 = pk[2*cp+1][0], b1 = pk[2*cp+1][1];
            unsigned u0 = half ? a0 : b0;      // what my partner needs from me
            unsigned u1 = half ? a1 : b1;
            unsigned x0 = __shfl_xor(u0, 32);
            unsigned x1 = __shfl_xor(u1, 32);
            v4u fw;
            fw.x = half ? x0 : a0;
            fw.y = half ? x1 : a1;
            fw.z = half ? b0 : x0;
            fw.w = half ? b1 : x1;
            v8s pf = __builtin_bit_cast(v8s, fw);
            o0 = __builtin_amdgcn_mfma_f32_32x32x16_bf16(va[0][cp], pf, o0, 0, 0, 0);
            o1 = __builtin_amdgcn_mfma_f32_32x32x16_bf16(va[1][cp], pf, o1, 0, 0, 0);
        }

        // prefetch next V tile (coalesced; overlaps next QK^T + softmax)
        if (it + 1 < NKB) {
            const unsigned short* Vn = Vh + (size_t)(it + 1) * 8 * 512;
            #pragma unroll
            for (int hb = 0; hb < 2; ++hb)
                #pragma unroll
                for (int c = 0; c < 4; ++c)
                    va[hb][c] = *reinterpret_cast<const v8s*>(&Vn[(hb * 4 + c) * 512]);
        }
    }
    #undef STAGE_K

    // li total = own 32 keys + partner's 32 keys (same q)
    float inv = 1.0f / (li + __shfl_xor(li, 32));

    // O^T: lane holds q = q0+l31; rows hd = (reg&3)+8*(reg>>2)+4*half (+32 for o1)
    const int q = q0 + l31;
    size_t base = ((size_t)(b * SEQ + q)) * DIM + h * HD;
    #pragma unroll
    for (int g = 0; g < 4; ++g) {
        int hd0 = 8 * g + 4 * half;
        uint2 u0, u1;
        u0.x = pk2bf(o0[4*g+0] * inv, o0[4*g+1] * inv);
        u0.y = pk2bf(o0[4*g+2] * inv, o0[4*g+3] * inv);
        u1.x = pk2bf(o1[4*g+0] * inv, o1[4*g+1] * inv);
        u1.y = pk2bf(o1[4*g+2] * inv, o1[4*g+3] * inv);
        *reinterpret_cast<uint2*>(&ctx[base + hd0])      = u0;
        *reinterpret_cast<uint2*>(&ctx[base + 32 + hd0]) = u1;
    }
}

extern "C" void kernel_launch(void* const* d_in, const int* in_sizes, int n_in,
                              void* d_out, int out_size, void* d_ws, size_t ws_size,
                              hipStream_t stream) {
    const float* x  = (const float*)d_in[0];
    const float* qw = (const float*)d_in[1]; const float* qb = (const float*)d_in[2];
    const float* kw = (const float*)d_in[3]; const float* kb = (const float*)d_in[4];
    const float* vw = (const float*)d_in[5]; const float* vb = (const float*)d_in[6];
    const float* ow = (const float*)d_in[7]; const float* ob = (const float*)d_in[8];
    float* out = (float*)d_out;

    char* ws = (char*)d_ws;
    size_t off = 0;
    auto alloc = [&](size_t bytes) -> unsigned short* {
        unsigned short* p = (unsigned short*)(ws + off);
        off += (bytes + 255) & ~(size_t)255;
        return p;
    };
    const size_t XB = (size_t)MM * DIM * 2;
    const size_t WB = (size_t)DIM * DIM * 2;
    const size_t QB = (size_t)NB * NH * SEQ * HD * 2;

    unsigned short* xb  = alloc(XB);
    unsigned short* wqb = alloc(WB);
    unsigned short* wkb = alloc(WB);
    unsigned short* wvb = alloc(WB);
    unsigned short* wob = alloc(WB);
    unsigned short* Qb  = alloc(QB);
    unsigned short* Kb  = alloc(QB);
    unsigned short* Vfb = alloc(QB);   // fragment-native V
    unsigned short* ctx = alloc(XB);

    const int n4x = MM * DIM / 4;
    const int n4w = DIM * DIM / 4;
    cast_f32_bf16<<<(n4x + 255) / 256, 256, 0, stream>>>(x, xb, n4x);
    cast4_f32_bf16<<<dim3((n4w + 255) / 256, 4), 256, 0, stream>>>(
        qw, kw, vw, ow, wqb, wkb, wvb, wob, n4w);

    gemm_qkv<<<dim3(MM / 128, 18), 256, 0, stream>>>(
        xb, wqb, wkb, wvb, qb, kb, vb, Qb, Kb, Vfb);

    attn<<<dim3(SEQ / 128, NB * NH), 256, 0, stream>>>(Qb, Kb, Vfb, ctx);

    gemm_o<<<dim3(MM / 128, DIM / 128), 256, 0, stream>>>(ctx, wob, ob, out);
}

// Round 7
// 228.663 us; speedup vs baseline: 1.1887x; 1.0237x over previous
//
#include <hip/hip_runtime.h>
#include <hip/hip_bf16.h>

#define NH  12
#define HD  64
#define DIM 768
#define SEQ 2048
#define NB  4
#define MM  (NB*SEQ)   // 8192 rows
#define NKB (SEQ/64)   // 32 key-blocks per head

typedef short    v8s  __attribute__((ext_vector_type(8)));   // 8 x bf16 (4 VGPRs)
typedef float    v4f  __attribute__((ext_vector_type(4)));
typedef float    v16f __attribute__((ext_vector_type(16)));
typedef unsigned v4u  __attribute__((ext_vector_type(4)));

#if __has_builtin(__builtin_amdgcn_exp2f)
#define EXP2(x) __builtin_amdgcn_exp2f(x)
#else
#define EXP2(x) __builtin_exp2f(x)
#endif

// round-to-nearest-even f32 -> bf16
static __device__ __forceinline__ unsigned short f2b(float f) {
    unsigned int u = __float_as_uint(f);
    return (unsigned short)((u + 0x7FFFu + ((u >> 16) & 1u)) >> 16);
}
// pack two f32 -> (bf16 lo | bf16 hi<<16), round-ties-away: 2 add + 1 perm
static __device__ __forceinline__ unsigned pk2bf(float lo, float hi) {
    return __builtin_amdgcn_perm(__float_as_uint(hi) + 0x8000u,
                                 __float_as_uint(lo) + 0x8000u, 0x07060302u);
}
// async global->LDS DMA, 16B/lane; LDS base wave-uniform, writes base+lane*16
static __device__ __forceinline__ void g2l16(const unsigned short* g, unsigned short* l) {
    __builtin_amdgcn_global_load_lds(
        (const __attribute__((address_space(1))) void*)g,
        (__attribute__((address_space(3))) void*)l, 16, 0, 0);
}

__global__ void cast_f32_bf16(const float* __restrict__ in,
                              unsigned short* __restrict__ out, int n4) {
    int i = blockIdx.x * blockDim.x + threadIdx.x;
    if (i < n4) {
        float4 v = reinterpret_cast<const float4*>(in)[i];
        ushort4 o;
        o.x = f2b(v.x); o.y = f2b(v.y); o.z = f2b(v.z); o.w = f2b(v.w);
        reinterpret_cast<ushort4*>(out)[i] = o;
    }
}

__global__ void cast4_f32_bf16(const float* __restrict__ i0, const float* __restrict__ i1,
                               const float* __restrict__ i2, const float* __restrict__ i3,
                               unsigned short* __restrict__ o0, unsigned short* __restrict__ o1,
                               unsigned short* __restrict__ o2, unsigned short* __restrict__ o3,
                               int n4) {
    int i = blockIdx.x * blockDim.x + threadIdx.x;
    if (i >= n4) return;
    const float* in; unsigned short* out;
    switch (blockIdx.y) {
        case 0: in = i0; out = o0; break;
        case 1: in = i1; out = o1; break;
        case 2: in = i2; out = o2; break;
        default: in = i3; out = o3; break;
    }
    float4 v = reinterpret_cast<const float4*>(in)[i];
    ushort4 o;
    o.x = f2b(v.x); o.y = f2b(v.y); o.z = f2b(v.z); o.w = f2b(v.w);
    reinterpret_cast<ushort4*>(out)[i] = o;
}

// Merged QKV: grid (MM/128, NH). One block computes Q,K,V for 128 rows x one
// head (64 features). A staged once per kb; 3 weight tiles; 48 MFMA/phase/wave.
// LDS 40KB -> 3 WG/CU (grid-matched). V written fragment-native for attn.
__global__ __launch_bounds__(256, 3) void gemm_qkv(
    const unsigned short* __restrict__ A,
    const unsigned short* __restrict__ Wq,
    const unsigned short* __restrict__ Wk,
    const unsigned short* __restrict__ Wv,
    const float* __restrict__ bq,
    const float* __restrict__ bk,
    const float* __restrict__ bvp,
    unsigned short* __restrict__ Qb,
    unsigned short* __restrict__ Kb,
    unsigned short* __restrict__ Vf)
{
    __shared__ __align__(16) unsigned short As[128 * 64];      // 16 KB
    __shared__ __align__(16) unsigned short Bs[3][64 * 64];    // 24 KB

    const int tid  = threadIdx.x;
    const int w    = tid >> 6, lane = tid & 63;
    const int quad = lane >> 4, l16 = lane & 15;
    const int wm   = w & 1,  wn = w >> 1;
    const int lane8 = lane >> 3, sc = lane & 7;
    const int m0   = blockIdx.x * 128;
    const int h    = blockIdx.y;
    const int n0   = h * 64;

    v4f acc[3][4][2];
    #pragma unroll
    for (int s = 0; s < 3; ++s)
        #pragma unroll
        for (int i = 0; i < 4; ++i)
            #pragma unroll
            for (int j = 0; j < 2; ++j)
                acc[s][i][j] = v4f{0.f, 0.f, 0.f, 0.f};

    for (int kb = 0; kb < DIM; kb += 64) {
        __syncthreads();
        #pragma unroll
        for (int t = 0; t < 4; ++t) {
            int r8 = w * 32 + t * 8;
            int r  = r8 + lane8;
            int gch = sc ^ (r & 7);
            g2l16(&A[(size_t)(m0 + r) * DIM + kb + gch * 8], &As[r8 * 64]);
        }
        #pragma unroll
        for (int u = 0; u < 6; ++u) {
            int G = w * 6 + u;               // 0..23: set = G>>3, rowgrp = G&7
            int set = G >> 3, rg = G & 7;
            int row = rg * 8 + lane8;
            int gch = sc ^ (row & 7);
            const unsigned short* Wp = (set == 0) ? Wq : (set == 1) ? Wk : Wv;
            g2l16(&Wp[(size_t)(n0 + row) * DIM + kb + gch * 8], &Bs[set][rg * 8 * 64]);
        }
        __syncthreads();
        #pragma unroll
        for (int kk = 0; kk < 64; kk += 32) {
            int chb = kk >> 3;
            v8s a[4];
            #pragma unroll
            for (int i = 0; i < 4; ++i) {
                int m = wm * 64 + i * 16 + l16;
                a[i] = *reinterpret_cast<const v8s*>(
                    &As[m * 64 + (((chb + quad) ^ (m & 7)) << 3)]);
            }
            #pragma unroll
            for (int s = 0; s < 3; ++s) {
                v8s b[2];
                #pragma unroll
                for (int j = 0; j < 2; ++j) {
                    int n = wn * 32 + j * 16 + l16;
                    b[j] = *reinterpret_cast<const v8s*>(
                        &Bs[s][n * 64 + (((chb + quad) ^ (n & 7)) << 3)]);
                }
                #pragma unroll
                for (int i = 0; i < 4; ++i)
                    #pragma unroll
                    for (int j = 0; j < 2; ++j)
                        acc[s][i][j] = __builtin_amdgcn_mfma_f32_16x16x32_bf16(
                            a[i], b[j], acc[s][i][j], 0, 0, 0);
            }
        }
    }

    // ---- epilogues ----
    // Q (scaled by 0.125*log2e) and K: [bh][s][hd] scatter
    #pragma unroll
    for (int s = 0; s < 2; ++s) {
        unsigned short* out = s ? Kb : Qb;
        const float* bias   = s ? bk : bq;
        const float scale   = s ? 1.0f : 0.1803368801f;
        #pragma unroll
        for (int i = 0; i < 4; ++i) {
            #pragma unroll
            for (int j = 0; j < 2; ++j) {
                int hd = wn * 32 + j * 16 + l16;
                float bias_v = bias[n0 + hd];
                #pragma unroll
                for (int r = 0; r < 4; ++r) {
                    int gm = m0 + wm * 64 + i * 16 + quad * 4 + r;
                    int bb = gm >> 11, sq = gm & (SEQ - 1);
                    out[((size_t)(bb * NH + h) * SEQ + sq) * HD + hd] =
                        f2b((acc[s][i][j][r] + bias_v) * scale);
                }
            }
        }
    }
    // V: fragment-native Vf[bh][kbi][hb*4+c][lane][8]
    #pragma unroll
    for (int i = 0; i < 4; ++i) {
        #pragma unroll
        for (int j = 0; j < 2; ++j) {
            int hd = wn * 32 + j * 16 + l16;
            int hb = hd >> 5, l31v = hd & 31;
            float bias_v = bvp[n0 + hd];
            int gm0 = m0 + wm * 64 + i * 16 + quad * 4;
            int bb = gm0 >> 11, sk = gm0 & (SEQ - 1);
            int kbi = sk >> 6;
            int halfv = quad >> 1, j0 = (quad & 1) * 4;
            ushort4 pkv;
            pkv.x = f2b(acc[2][i][j][0] + bias_v);
            pkv.y = f2b(acc[2][i][j][1] + bias_v);
            pkv.z = f2b(acc[2][i][j][2] + bias_v);
            pkv.w = f2b(acc[2][i][j][3] + bias_v);
            size_t frag = ((size_t)(bb * NH + h) * NKB + kbi) * 8 + hb * 4 + i;
            *reinterpret_cast<ushort4*>(
                &Vf[frag * 512 + (halfv * 32 + l31v) * 8 + j0]) = pkv;
        }
    }
}

// Output projection: 128x128 tiles, f32 out. grid (64, 6).
__global__ __launch_bounds__(256) void gemm_o(
    const unsigned short* __restrict__ A,
    const unsigned short* __restrict__ W,
    const float* __restrict__ bias,
    float* __restrict__ out)
{
    __shared__ __align__(16) unsigned short As[128 * 64];
    __shared__ __align__(16) unsigned short Bs[128 * 64];

    const int tid  = threadIdx.x;
    const int w    = tid >> 6, lane = tid & 63;
    const int quad = lane >> 4, l16 = lane & 15;
    const int wm   = w & 1,  wn = w >> 1;
    const int lane8 = lane >> 3, sc = lane & 7;
    const int m0  = blockIdx.x * 128;
    const int n0l = blockIdx.y * 128;

    v4f acc[4][4];
    #pragma unroll
    for (int i = 0; i < 4; ++i)
        #pragma unroll
        for (int j = 0; j < 4; ++j)
            acc[i][j] = v4f{0.f, 0.f, 0.f, 0.f};

    for (int kb = 0; kb < DIM; kb += 64) {
        __syncthreads();
        #pragma unroll
        for (int t = 0; t < 4; ++t) {
            int r8 = w * 32 + t * 8;
            int r  = r8 + lane8;
            int gch = sc ^ (r & 7);
            g2l16(&A[(size_t)(m0  + r) * DIM + kb + gch * 8], &As[r8 * 64]);
            g2l16(&W[(size_t)(n0l + r) * DIM + kb + gch * 8], &Bs[r8 * 64]);
        }
        __syncthreads();
        #pragma unroll
        for (int kk = 0; kk < 64; kk += 32) {
            v8s a[4], b[4];
            int chb = kk >> 3;
            #pragma unroll
            for (int i = 0; i < 4; ++i) {
                int m = wm * 64 + i * 16 + l16;
                a[i] = *reinterpret_cast<const v8s*>(
                    &As[m * 64 + (((chb + quad) ^ (m & 7)) << 3)]);
                int n = wn * 64 + i * 16 + l16;
                b[i] = *reinterpret_cast<const v8s*>(
                    &Bs[n * 64 + (((chb + quad) ^ (n & 7)) << 3)]);
            }
            #pragma unroll
            for (int i = 0; i < 4; ++i)
                #pragma unroll
                for (int j = 0; j < 4; ++j)
                    acc[i][j] = __builtin_amdgcn_mfma_f32_16x16x32_bf16(a[i], b[j], acc[i][j], 0, 0, 0);
        }
    }

    #pragma unroll
    for (int i = 0; i < 4; ++i) {
        #pragma unroll
        for (int j = 0; j < 4; ++j) {
            int gn = n0l + wn * 64 + j * 16 + l16;
            float bias_v = bias[gn];
            #pragma unroll
            for (int r = 0; r < 4; ++r) {
                int gm = m0 + wm * 64 + i * 16 + quad * 4 + r;
                out[(size_t)gm * DIM + gn] = acc[i][j][r] + bias_v;
            }
        }
    }
}

// Transposed flash attention. V register-fragments double-buffered: next tile's
// V loads issued RIGHT AFTER the barrier (full compute phase of latency cover
// before the next barrier's vmcnt(0) drain). K in LDS dbuf (16KB).
__global__ __launch_bounds__(256, 3) void attn(
    const unsigned short* __restrict__ Q,
    const unsigned short* __restrict__ K,
    const unsigned short* __restrict__ Vf,
    unsigned short* __restrict__ ctx)
{
    __shared__ __align__(16) unsigned short Ks[2][64 * 64];   // 16 KB

    const int tid  = threadIdx.x;
    const int w    = tid >> 6, lane = tid & 63;
    const int l31  = lane & 31, half = lane >> 5;
    const int lane8 = lane >> 3, sc = lane & 7;
    const int bh   = blockIdx.y;
    const int b    = bh / NH, h = bh % NH;
    const int q0   = blockIdx.x * 128 + w * 32;

    const unsigned short* Qp = Q  + ((size_t)bh * SEQ + q0) * HD;
    const unsigned short* Kp = K  + (size_t)bh * SEQ * HD;
    const unsigned short* Vh = Vf + (size_t)bh * NKB * 8 * 512 + lane * 8;

    // Q B-frag: B[n=q=l31][k = c*16 + half*8 + j] (pre-scaled by 0.125*log2e)
    v8s bq[4];
    #pragma unroll
    for (int c = 0; c < 4; ++c)
        bq[c] = *reinterpret_cast<const v8s*>(&Qp[l31 * HD + c * 16 + half * 8]);

    v8s va[2][4], vb[2][4];
    #pragma unroll
    for (int hb = 0; hb < 2; ++hb)
        #pragma unroll
        for (int c = 0; c < 4; ++c)
            va[hb][c] = *reinterpret_cast<const v8s*>(&Vh[(hb * 4 + c) * 512]);

    v16f o0, o1, Z;
    #pragma unroll
    for (int i = 0; i < 16; ++i) { o0[i] = 0.f; o1[i] = 0.f; Z[i] = 0.f; }
    float li = 0.f;

    const int rx = l31 & 7;
    int rdoff[4];
    #pragma unroll
    for (int c = 0; c < 4; ++c)
        rdoff[c] = l31 * 64 + (((c * 2 + half) ^ rx) << 3);

    #define STAGE_K(kb_, buf_)                                                       \
        do {                                                                         \
            _Pragma("unroll")                                                        \
            for (int t = 0; t < 2; ++t) {                                            \
                int r8  = (t * 4 + w) * 8;                                           \
                int row = r8 + lane8;                                                \
                int gch = sc ^ (row & 7);                                            \
                g2l16(&Kp[(size_t)((kb_) + row) * HD + gch * 8], &Ks[buf_][r8 * 64]);\
            }                                                                        \
        } while (0)

    #define TILE(IT, BUF, VCUR, VNEXT)                                               \
    {                                                                                \
        __syncthreads();                                                             \
        if ((IT) + 1 < NKB) {                                                        \
            STAGE_K(((IT) + 1) * 64, (BUF) ^ 1);                                     \
            const unsigned short* Vn = Vh + (size_t)((IT) + 1) * 8 * 512;            \
            _Pragma("unroll")                                                        \
            for (int hb = 0; hb < 2; ++hb)                                           \
                _Pragma("unroll")                                                    \
                for (int c = 0; c < 4; ++c)                                          \
                    VNEXT[hb][c] = *reinterpret_cast<const v8s*>(&Vn[(hb*4+c)*512]); \
        }                                                                            \
        v16f s0, s1;                                                                 \
        {                                                                            \
            v8s ka0 = *reinterpret_cast<const v8s*>(&Ks[BUF][rdoff[0]]);             \
            v8s ka1 = *reinterpret_cast<const v8s*>(&Ks[BUF][rdoff[0] + 2048]);      \
            s0 = __builtin_amdgcn_mfma_f32_32x32x16_bf16(ka0, bq[0], Z, 0, 0, 0);    \
            s1 = __builtin_amdgcn_mfma_f32_32x32x16_bf16(ka1, bq[0], Z, 0, 0, 0);    \
            _Pragma("unroll")                                                        \
            for (int c = 1; c < 4; ++c) {                                            \
                v8s k0 = *reinterpret_cast<const v8s*>(&Ks[BUF][rdoff[c]]);          \
                v8s k1 = *reinterpret_cast<const v8s*>(&Ks[BUF][rdoff[c] + 2048]);   \
                s0 = __builtin_amdgcn_mfma_f32_32x32x16_bf16(k0, bq[c], s0, 0, 0, 0);\
                s1 = __builtin_amdgcn_mfma_f32_32x32x16_bf16(k1, bq[c], s1, 0, 0, 0);\
            }                                                                        \
        }                                                                            \
        unsigned pk[8][2];                                                           \
        _Pragma("unroll")                                                            \
        for (int g = 0; g < 4; ++g) {                                                \
            float e0 = EXP2(s0[4*g+0]), e1 = EXP2(s0[4*g+1]);                        \
            float e2 = EXP2(s0[4*g+2]), e3 = EXP2(s0[4*g+3]);                        \
            li += (e0 + e1) + (e2 + e3);                                             \
            pk[g][0] = pk2bf(e0, e1);                                                \
            pk[g][1] = pk2bf(e2, e3);                                                \
            float f0 = EXP2(s1[4*g+0]), f1 = EXP2(s1[4*g+1]);                        \
            float f2 = EXP2(s1[4*g+2]), f3 = EXP2(s1[4*g+3]);                        \
            li += (f0 + f1) + (f2 + f3);                                             \
            pk[4+g][0] = pk2bf(f0, f1);                                              \
            pk[4+g][1] = pk2bf(f2, f3);                                              \
        }                                                                            \
        _Pragma("unroll")                                                            \
        for (int cp = 0; cp < 4; ++cp) {                                             \
            unsigned a0 = pk[2*cp][0],   a1 = pk[2*cp][1];                           \
            unsigned b0 = pk[2*cp+1][0], b1 = pk[2*cp+1][1];                         \
            unsigned u0 = half ? a0 : b0;                                            \
            unsigned u1 = half ? a1 : b1;                                            \
            unsigned x0 = __shfl_xor(u0, 32);                                        \
            unsigned x1 = __shfl_xor(u1, 32);                                        \
            v4u fw;                                                                  \
            fw.x = half ? x0 : a0;                                                   \
            fw.y = half ? x1 : a1;                                                   \
            fw.z = half ? b0 : x0;                                                   \
            fw.w = half ? b1 : x1;                                                   \
            v8s pf = __builtin_bit_cast(v8s, fw);                                    \
            o0 = __builtin_amdgcn_mfma_f32_32x32x16_bf16(VCUR[0][cp], pf, o0, 0,0,0);\
            o1 = __builtin_amdgcn_mfma_f32_32x32x16_bf16(VCUR[1][cp], pf, o1, 0,0,0);\
        }                                                                            \
    }

    STAGE_K(0, 0);

    for (int it = 0; it < NKB; it += 2) {
        TILE(it,     0, va, vb)
        TILE(it + 1, 1, vb, va)
    }
    #undef TILE
    #undef STAGE_K

    float inv = 1.0f / (li + __shfl_xor(li, 32));

    const int q = q0 + l31;
    size_t base = ((size_t)(b * SEQ + q)) * DIM + h * HD;
    #pragma unroll
    for (int g = 0; g < 4; ++g) {
        int hd0 = 8 * g + 4 * half;
        uint2 u0, u1;
        u0.x = pk2bf(o0[4*g+0] * inv, o0[4*g+1] * inv);
        u0.y = pk2bf(o0[4*g+2] * inv, o0[4*g+3] * inv);
        u1.x = pk2bf(o1[4*g+0] * inv, o1[4*g+1] * inv);
        u1.y = pk2bf(o1[4*g+2] * inv, o1[4*g+3] * inv);
        *reinterpret_cast<uint2*>(&ctx[base + hd0])      = u0;
        *reinterpret_cast<uint2*>(&ctx[base + 32 + hd0]) = u1;
    }
}

extern "C" void kernel_launch(void* const* d_in, const int* in_sizes, int n_in,
                              void* d_out, int out_size, void* d_ws, size_t ws_size,
                              hipStream_t stream) {
    const float* x  = (const float*)d_in[0];
    const float* qw = (const float*)d_in[1]; const float* qb = (const float*)d_in[2];
    const float* kw = (const float*)d_in[3]; const float* kb = (const float*)d_in[4];
    const float* vw = (const float*)d_in[5]; const float* vb = (const float*)d_in[6];
    const float* ow = (const float*)d_in[7]; const float* ob = (const float*)d_in[8];
    float* out = (float*)d_out;

    char* ws = (char*)d_ws;
    size_t off = 0;
    auto alloc = [&](size_t bytes) -> unsigned short* {
        unsigned short* p = (unsigned short*)(ws + off);
        off += (bytes + 255) & ~(size_t)255;
        return p;
    };
    const size_t XB = (size_t)MM * DIM * 2;
    const size_t WB = (size_t)DIM * DIM * 2;
    const size_t QB = (size_t)NB * NH * SEQ * HD * 2;

    unsigned short* xb  = alloc(XB);
    unsigned short* wqb = alloc(WB);
    unsigned short* wkb = alloc(WB);
    unsigned short* wvb = alloc(WB);
    unsigned short* wob = alloc(WB);
    unsigned short* Qb  = alloc(QB);
    unsigned short* Kb  = alloc(QB);
    unsigned short* Vfb = alloc(QB);   // fragment-native V
    unsigned short* ctx = alloc(XB);

    const int n4x = MM * DIM / 4;
    const int n4w = DIM * DIM / 4;
    cast_f32_bf16<<<(n4x + 255) / 256, 256, 0, stream>>>(x, xb, n4x);
    cast4_f32_bf16<<<dim3((n4w + 255) / 256, 4), 256, 0, stream>>>(
        qw, kw, vw, ow, wqb, wkb, wvb, wob, n4w);

    gemm_qkv<<<dim3(MM / 128, NH), 256, 0, stream>>>(
        xb, wqb, wkb, wvb, qb, kb, vb, Qb, Kb, Vfb);

    attn<<<dim3(SEQ / 128, NB * NH), 256, 0, stream>>>(Qb, Kb, Vfb, ctx);

    gemm_o<<<dim3(MM / 128, DIM / 128), 256, 0, stream>>>(ctx, wob, ob, out);
}

// Round 8
// 208.673 us; speedup vs baseline: 1.3025x; 1.0958x over previous
//
#include <hip/hip_runtime.h>
#include <hip/hip_bf16.h>

#define NH  12
#define HD  64
#define DIM 768
#define SEQ 2048
#define NB  4
#define MM  (NB*SEQ)   // 8192 rows
#define NKB (SEQ/64)   // 32 key-blocks per head

typedef short    v8s  __attribute__((ext_vector_type(8)));   // 8 x bf16 (4 VGPRs)
typedef float    v4f  __attribute__((ext_vector_type(4)));
typedef float    v16f __attribute__((ext_vector_type(16)));
typedef unsigned v4u  __attribute__((ext_vector_type(4)));

#if __has_builtin(__builtin_amdgcn_exp2f)
#define EXP2(x) __builtin_amdgcn_exp2f(x)
#else
#define EXP2(x) __builtin_exp2f(x)
#endif

// round-to-nearest-even f32 -> bf16
static __device__ __forceinline__ unsigned short f2b(float f) {
    unsigned int u = __float_as_uint(f);
    return (unsigned short)((u + 0x7FFFu + ((u >> 16) & 1u)) >> 16);
}
// pack two f32 -> (bf16 lo | bf16 hi<<16), round-ties-away: 2 add + 1 perm
static __device__ __forceinline__ unsigned pk2bf(float lo, float hi) {
    return __builtin_amdgcn_perm(__float_as_uint(hi) + 0x8000u,
                                 __float_as_uint(lo) + 0x8000u, 0x07060302u);
}
// async global->LDS DMA, 16B/lane; LDS base wave-uniform, writes base+lane*16
static __device__ __forceinline__ void g2l16(const unsigned short* g, unsigned short* l) {
    __builtin_amdgcn_global_load_lds(
        (const __attribute__((address_space(1))) void*)g,
        (__attribute__((address_space(3))) void*)l, 16, 0, 0);
}

__global__ void cast_f32_bf16(const float* __restrict__ in,
                              unsigned short* __restrict__ out, int n4) {
    int i = blockIdx.x * blockDim.x + threadIdx.x;
    if (i < n4) {
        float4 v = reinterpret_cast<const float4*>(in)[i];
        ushort4 o;
        o.x = f2b(v.x); o.y = f2b(v.y); o.z = f2b(v.z); o.w = f2b(v.w);
        reinterpret_cast<ushort4*>(out)[i] = o;
    }
}

__global__ void cast4_f32_bf16(const float* __restrict__ i0, const float* __restrict__ i1,
                               const float* __restrict__ i2, const float* __restrict__ i3,
                               unsigned short* __restrict__ o0, unsigned short* __restrict__ o1,
                               unsigned short* __restrict__ o2, unsigned short* __restrict__ o3,
                               int n4) {
    int i = blockIdx.x * blockDim.x + threadIdx.x;
    if (i >= n4) return;
    const float* in; unsigned short* out;
    switch (blockIdx.y) {
        case 0: in = i0; out = o0; break;
        case 1: in = i1; out = o1; break;
        case 2: in = i2; out = o2; break;
        default: in = i3; out = o3; break;
    }
    float4 v = reinterpret_cast<const float4*>(in)[i];
    ushort4 o;
    o.x = f2b(v.x); o.y = f2b(v.y); o.z = f2b(v.z); o.w = f2b(v.w);
    reinterpret_cast<ushort4*>(out)[i] = o;
}

// Merged QKV: grid (MM/128, NH). One block computes Q,K,V for 128 rows x one
// head (64 features). A staged once per kb; 3 weight tiles; 48 MFMA/phase/wave.
__global__ __launch_bounds__(256, 3) void gemm_qkv(
    const unsigned short* __restrict__ A,
    const unsigned short* __restrict__ Wq,
    const unsigned short* __restrict__ Wk,
    const unsigned short* __restrict__ Wv,
    const float* __restrict__ bq,
    const float* __restrict__ bk,
    const float* __restrict__ bvp,
    unsigned short* __restrict__ Qb,
    unsigned short* __restrict__ Kb,
    unsigned short* __restrict__ Vf)
{
    __shared__ __align__(16) unsigned short As[128 * 64];      // 16 KB
    __shared__ __align__(16) unsigned short Bs[3][64 * 64];    // 24 KB

    const int tid  = threadIdx.x;
    const int w    = tid >> 6, lane = tid & 63;
    const int quad = lane >> 4, l16 = lane & 15;
    const int wm   = w & 1,  wn = w >> 1;
    const int lane8 = lane >> 3, sc = lane & 7;
    const int m0   = blockIdx.x * 128;
    const int h    = blockIdx.y;
    const int n0   = h * 64;

    v4f acc[3][4][2];
    #pragma unroll
    for (int s = 0; s < 3; ++s)
        #pragma unroll
        for (int i = 0; i < 4; ++i)
            #pragma unroll
            for (int j = 0; j < 2; ++j)
                acc[s][i][j] = v4f{0.f, 0.f, 0.f, 0.f};

    for (int kb = 0; kb < DIM; kb += 64) {
        __syncthreads();
        #pragma unroll
        for (int t = 0; t < 4; ++t) {
            int r8 = w * 32 + t * 8;
            int r  = r8 + lane8;
            int gch = sc ^ (r & 7);
            g2l16(&A[(size_t)(m0 + r) * DIM + kb + gch * 8], &As[r8 * 64]);
        }
        #pragma unroll
        for (int u = 0; u < 6; ++u) {
            int G = w * 6 + u;               // 0..23: set = G>>3, rowgrp = G&7
            int set = G >> 3, rg = G & 7;
            int row = rg * 8 + lane8;
            int gch = sc ^ (row & 7);
            const unsigned short* Wp = (set == 0) ? Wq : (set == 1) ? Wk : Wv;
            g2l16(&Wp[(size_t)(n0 + row) * DIM + kb + gch * 8], &Bs[set][rg * 8 * 64]);
        }
        __syncthreads();
        #pragma unroll
        for (int kk = 0; kk < 64; kk += 32) {
            int chb = kk >> 3;
            v8s a[4];
            #pragma unroll
            for (int i = 0; i < 4; ++i) {
                int m = wm * 64 + i * 16 + l16;
                a[i] = *reinterpret_cast<const v8s*>(
                    &As[m * 64 + (((chb + quad) ^ (m & 7)) << 3)]);
            }
            #pragma unroll
            for (int s = 0; s < 3; ++s) {
                v8s b[2];
                #pragma unroll
                for (int j = 0; j < 2; ++j) {
                    int n = wn * 32 + j * 16 + l16;
                    b[j] = *reinterpret_cast<const v8s*>(
                        &Bs[s][n * 64 + (((chb + quad) ^ (n & 7)) << 3)]);
                }
                #pragma unroll
                for (int i = 0; i < 4; ++i)
                    #pragma unroll
                    for (int j = 0; j < 2; ++j)
                        acc[s][i][j] = __builtin_amdgcn_mfma_f32_16x16x32_bf16(
                            a[i], b[j], acc[s][i][j], 0, 0, 0);
            }
        }
    }

    // ---- epilogues ----
    #pragma unroll
    for (int s = 0; s < 2; ++s) {
        unsigned short* out = s ? Kb : Qb;
        const float* bias   = s ? bk : bq;
        const float scale   = s ? 1.0f : 0.1803368801f;
        #pragma unroll
        for (int i = 0; i < 4; ++i) {
            #pragma unroll
            for (int j = 0; j < 2; ++j) {
                int hd = wn * 32 + j * 16 + l16;
                float bias_v = bias[n0 + hd];
                #pragma unroll
                for (int r = 0; r < 4; ++r) {
                    int gm = m0 + wm * 64 + i * 16 + quad * 4 + r;
                    int bb = gm >> 11, sq = gm & (SEQ - 1);
                    out[((size_t)(bb * NH + h) * SEQ + sq) * HD + hd] =
                        f2b((acc[s][i][j][r] + bias_v) * scale);
                }
            }
        }
    }
    // V: fragment-native Vf[bh][kbi][hb*4+c][lane][8]
    #pragma unroll
    for (int i = 0; i < 4; ++i) {
        #pragma unroll
        for (int j = 0; j < 2; ++j) {
            int hd = wn * 32 + j * 16 + l16;
            int hb = hd >> 5, l31v = hd & 31;
            float bias_v = bvp[n0 + hd];
            int gm0 = m0 + wm * 64 + i * 16 + quad * 4;
            int bb = gm0 >> 11, sk = gm0 & (SEQ - 1);
            int kbi = sk >> 6;
            int halfv = quad >> 1, j0 = (quad & 1) * 4;
            ushort4 pkv;
            pkv.x = f2b(acc[2][i][j][0] + bias_v);
            pkv.y = f2b(acc[2][i][j][1] + bias_v);
            pkv.z = f2b(acc[2][i][j][2] + bias_v);
            pkv.w = f2b(acc[2][i][j][3] + bias_v);
            size_t frag = ((size_t)(bb * NH + h) * NKB + kbi) * 8 + hb * 4 + i;
            *reinterpret_cast<ushort4*>(
                &Vf[frag * 512 + (halfv * 32 + l31v) * 8 + j0]) = pkv;
        }
    }
}

// Output projection: 128x64 tiles, grid (64, 12) = 768 blocks = 3 WG/CU even.
__global__ __launch_bounds__(256, 3) void gemm_o(
    const unsigned short* __restrict__ A,
    const unsigned short* __restrict__ W,
    const float* __restrict__ bias,
    float* __restrict__ out)
{
    __shared__ __align__(16) unsigned short As[128 * 64];   // 16 KB
    __shared__ __align__(16) unsigned short Bs[64 * 64];    // 8 KB

    const int tid  = threadIdx.x;
    const int w    = tid >> 6, lane = tid & 63;
    const int quad = lane >> 4, l16 = lane & 15;
    const int wm   = w & 1,  wn = w >> 1;
    const int lane8 = lane >> 3, sc = lane & 7;
    const int m0  = blockIdx.x * 128;
    const int n0l = blockIdx.y * 64;

    v4f acc[4][2];
    #pragma unroll
    for (int i = 0; i < 4; ++i)
        #pragma unroll
        for (int j = 0; j < 2; ++j)
            acc[i][j] = v4f{0.f, 0.f, 0.f, 0.f};

    for (int kb = 0; kb < DIM; kb += 64) {
        __syncthreads();
        #pragma unroll
        for (int t = 0; t < 4; ++t) {
            int r8 = w * 32 + t * 8;
            int r  = r8 + lane8;
            int gch = sc ^ (r & 7);
            g2l16(&A[(size_t)(m0 + r) * DIM + kb + gch * 8], &As[r8 * 64]);
        }
        #pragma unroll
        for (int t = 0; t < 2; ++t) {
            int r8 = (w * 2 + t) * 8;
            int r  = r8 + lane8;
            int gch = sc ^ (r & 7);
            g2l16(&W[(size_t)(n0l + r) * DIM + kb + gch * 8], &Bs[r8 * 64]);
        }
        __syncthreads();
        #pragma unroll
        for (int kk = 0; kk < 64; kk += 32) {
            v8s a[4], b[2];
            int chb = kk >> 3;
            #pragma unroll
            for (int i = 0; i < 4; ++i) {
                int m = wm * 64 + i * 16 + l16;
                a[i] = *reinterpret_cast<const v8s*>(
                    &As[m * 64 + (((chb + quad) ^ (m & 7)) << 3)]);
            }
            #pragma unroll
            for (int j = 0; j < 2; ++j) {
                int n = wn * 32 + j * 16 + l16;
                b[j] = *reinterpret_cast<const v8s*>(
                    &Bs[n * 64 + (((chb + quad) ^ (n & 7)) << 3)]);
            }
            #pragma unroll
            for (int i = 0; i < 4; ++i)
                #pragma unroll
                for (int j = 0; j < 2; ++j)
                    acc[i][j] = __builtin_amdgcn_mfma_f32_16x16x32_bf16(a[i], b[j], acc[i][j], 0, 0, 0);
        }
    }

    #pragma unroll
    for (int i = 0; i < 4; ++i) {
        #pragma unroll
        for (int j = 0; j < 2; ++j) {
            int gn = n0l + wn * 32 + j * 16 + l16;
            float bias_v = bias[gn];
            #pragma unroll
            for (int r = 0; r < 4; ++r) {
                int gm = m0 + wm * 64 + i * 16 + quad * 4 + r;
                out[(size_t)gm * DIM + gn] = acc[i][j][r] + bias_v;
            }
        }
    }
}

// Transposed flash attention (R6 version: single V buffer, no spill).
// S^T = mfma(A=K, B=Q), lane owns one q-column, softmax lane-local, P^T built
// in registers (2 shfl_xor(32)/cp), V read as coalesced fragment-native global
// loads (prefetched at end of tile), K in LDS dbuf (16KB).
__global__ __launch_bounds__(256, 3) void attn(
    const unsigned short* __restrict__ Q,
    const unsigned short* __restrict__ K,
    const unsigned short* __restrict__ Vf,
    unsigned short* __restrict__ ctx)
{
    __shared__ __align__(16) unsigned short Ks[2][64 * 64];   // 16 KB

    const int tid  = threadIdx.x;
    const int w    = tid >> 6, lane = tid & 63;
    const int l31  = lane & 31, half = lane >> 5;
    const int lane8 = lane >> 3, sc = lane & 7;
    const int bh   = blockIdx.y;
    const int b    = bh / NH, h = bh % NH;
    const int q0   = blockIdx.x * 128 + w * 32;

    const unsigned short* Qp = Q  + ((size_t)bh * SEQ + q0) * HD;
    const unsigned short* Kp = K  + (size_t)bh * SEQ * HD;
    const unsigned short* Vh = Vf + (size_t)bh * NKB * 8 * 512 + lane * 8;

    // Q B-frag: B[n=q=l31][k = c*16 + half*8 + j] (pre-scaled by 0.125*log2e)
    v8s bq[4];
    #pragma unroll
    for (int c = 0; c < 4; ++c)
        bq[c] = *reinterpret_cast<const v8s*>(&Qp[l31 * HD + c * 16 + half * 8]);

    // V A-frags for tile 0 (coalesced: consecutive lanes -> consecutive 16B)
    v8s va[2][4];
    #pragma unroll
    for (int hb = 0; hb < 2; ++hb)
        #pragma unroll
        for (int c = 0; c < 4; ++c)
            va[hb][c] = *reinterpret_cast<const v8s*>(&Vh[(hb * 4 + c) * 512]);

    v16f o0, o1, Z;
    #pragma unroll
    for (int i = 0; i < 16; ++i) { o0[i] = 0.f; o1[i] = 0.f; Z[i] = 0.f; }
    float li = 0.f;

    const int rx = l31 & 7;
    int rdoff[4];
    #pragma unroll
    for (int c = 0; c < 4; ++c)
        rdoff[c] = l31 * 64 + (((c * 2 + half) ^ rx) << 3);

    #define STAGE_K(kb_, buf_)                                                       \
        do {                                                                         \
            _Pragma("unroll")                                                        \
            for (int t = 0; t < 2; ++t) {                                            \
                int r8  = (t * 4 + w) * 8;                                           \
                int row = r8 + lane8;                                                \
                int gch = sc ^ (row & 7);                                            \
                g2l16(&Kp[(size_t)((kb_) + row) * HD + gch * 8], &Ks[buf_][r8 * 64]);\
            }                                                                        \
        } while (0)

    STAGE_K(0, 0);

    for (int it = 0; it < NKB; ++it) {
        const int buf = it & 1;
        __syncthreads();                        // drains K-DMA(it)
        if (it + 1 < NKB) STAGE_K((it + 1) * 64, buf ^ 1);

        // S^T[key][q]: s0 = keys 0..31 of tile, s1 = keys 32..63
        v16f s0, s1;
        {
            v8s ka00 = *reinterpret_cast<const v8s*>(&Ks[buf][rdoff[0]]);
            v8s ka10 = *reinterpret_cast<const v8s*>(&Ks[buf][rdoff[0] + 2048]);
            s0 = __builtin_amdgcn_mfma_f32_32x32x16_bf16(ka00, bq[0], Z, 0, 0, 0);
            s1 = __builtin_amdgcn_mfma_f32_32x32x16_bf16(ka10, bq[0], Z, 0, 0, 0);
            #pragma unroll
            for (int c = 1; c < 4; ++c) {
                v8s k0 = *reinterpret_cast<const v8s*>(&Ks[buf][rdoff[c]]);
                v8s k1 = *reinterpret_cast<const v8s*>(&Ks[buf][rdoff[c] + 2048]);
                s0 = __builtin_amdgcn_mfma_f32_32x32x16_bf16(k0, bq[c], s0, 0, 0, 0);
                s1 = __builtin_amdgcn_mfma_f32_32x32x16_bf16(k1, bq[c], s1, 0, 0, 0);
            }
        }

        // exp2 + lane-local li + pack key-pairs
        unsigned pk[8][2];
        #pragma unroll
        for (int g = 0; g < 4; ++g) {
            float e0 = EXP2(s0[4*g+0]), e1 = EXP2(s0[4*g+1]);
            float e2 = EXP2(s0[4*g+2]), e3 = EXP2(s0[4*g+3]);
            li += (e0 + e1) + (e2 + e3);
            pk[g][0] = pk2bf(e0, e1);
            pk[g][1] = pk2bf(e2, e3);
            float f0 = EXP2(s1[4*g+0]), f1 = EXP2(s1[4*g+1]);
            float f2 = EXP2(s1[4*g+2]), f3 = EXP2(s1[4*g+3]);
            li += (f0 + f1) + (f2 + f3);
            pk[4+g][0] = pk2bf(f0, f1);
            pk[4+g][1] = pk2bf(f2, f3);
        }

        // P^T B-frags: partner (lane^32) holds the complementary 4-key blocks.
        #pragma unroll
        for (int cp = 0; cp < 4; ++cp) {
            unsigned a0 = pk[2*cp][0],   a1 = pk[2*cp][1];
            unsigned b0 = pk[2*cp+1][0], b1 = pk[2*cp+1][1];
            unsigned u0 = half ? a0 : b0;      // what my partner needs from me
            unsigned u1 = half ? a1 : b1;
            unsigned x0 = __shfl_xor(u0, 32);
            unsigned x1 = __shfl_xor(u1, 32);
            v4u fw;
            fw.x = half ? x0 : a0;
            fw.y = half ? x1 : a1;
            fw.z = half ? b0 : x0;
            fw.w = half ? b1 : x1;
            v8s pf = __builtin_bit_cast(v8s, fw);
            o0 = __builtin_amdgcn_mfma_f32_32x32x16_bf16(va[0][cp], pf, o0, 0, 0, 0);
            o1 = __builtin_amdgcn_mfma_f32_32x32x16_bf16(va[1][cp], pf, o1, 0, 0, 0);
        }

        // prefetch next V tile (coalesced; overlaps next QK^T + softmax)
        if (it + 1 < NKB) {
            const unsigned short* Vn = Vh + (size_t)(it + 1) * 8 * 512;
            #pragma unroll
            for (int hb = 0; hb < 2; ++hb)
                #pragma unroll
                for (int c = 0; c < 4; ++c)
                    va[hb][c] = *reinterpret_cast<const v8s*>(&Vn[(hb * 4 + c) * 512]);
        }
    }
    #undef STAGE_K

    // li total = own 32 keys + partner's 32 keys (same q)
    float inv = 1.0f / (li + __shfl_xor(li, 32));

    // O^T: lane holds q = q0+l31; rows hd = (reg&3)+8*(reg>>2)+4*half (+32 for o1)
    const int q = q0 + l31;
    size_t base = ((size_t)(b * SEQ + q)) * DIM + h * HD;
    #pragma unroll
    for (int g = 0; g < 4; ++g) {
        int hd0 = 8 * g + 4 * half;
        uint2 u0, u1;
        u0.x = pk2bf(o0[4*g+0] * inv, o0[4*g+1] * inv);
        u0.y = pk2bf(o0[4*g+2] * inv, o0[4*g+3] * inv);
        u1.x = pk2bf(o1[4*g+0] * inv, o1[4*g+1] * inv);
        u1.y = pk2bf(o1[4*g+2] * inv, o1[4*g+3] * inv);
        *reinterpret_cast<uint2*>(&ctx[base + hd0])      = u0;
        *reinterpret_cast<uint2*>(&ctx[base + 32 + hd0]) = u1;
    }
}

extern "C" void kernel_launch(void* const* d_in, const int* in_sizes, int n_in,
                              void* d_out, int out_size, void* d_ws, size_t ws_size,
                              hipStream_t stream) {
    const float* x  = (const float*)d_in[0];
    const float* qw = (const float*)d_in[1]; const float* qb = (const float*)d_in[2];
    const float* kw = (const float*)d_in[3]; const float* kb = (const float*)d_in[4];
    const float* vw = (const float*)d_in[5]; const float* vb = (const float*)d_in[6];
    const float* ow = (const float*)d_in[7]; const float* ob = (const float*)d_in[8];
    float* out = (float*)d_out;

    char* ws = (char*)d_ws;
    size_t off = 0;
    auto alloc = [&](size_t bytes) -> unsigned short* {
        unsigned short* p = (unsigned short*)(ws + off);
        off += (bytes + 255) & ~(size_t)255;
        return p;
    };
    const size_t XB = (size_t)MM * DIM * 2;
    const size_t WB = (size_t)DIM * DIM * 2;
    const size_t QB = (size_t)NB * NH * SEQ * HD * 2;

    unsigned short* xb  = alloc(XB);
    unsigned short* wqb = alloc(WB);
    unsigned short* wkb = alloc(WB);
    unsigned short* wvb = alloc(WB);
    unsigned short* wob = alloc(WB);
    unsigned short* Qb  = alloc(QB);
    unsigned short* Kb  = alloc(QB);
    unsigned short* Vfb = alloc(QB);   // fragment-native V
    unsigned short* ctx = alloc(XB);

    const int n4x = MM * DIM / 4;
    const int n4w = DIM * DIM / 4;
    cast_f32_bf16<<<(n4x + 255) / 256, 256, 0, stream>>>(x, xb, n4x);
    cast4_f32_bf16<<<dim3((n4w + 255) / 256, 4), 256, 0, stream>>>(
        qw, kw, vw, ow, wqb, wkb, wvb, wob, n4w);

    gemm_qkv<<<dim3(MM / 128, NH), 256, 0, stream>>>(
        xb, wqb, wkb, wvb, qb, kb, vb, Qb, Kb, Vfb);

    attn<<<dim3(SEQ / 128, NB * NH), 256, 0, stream>>>(Qb, Kb, Vfb, ctx);

    gemm_o<<<dim3(MM / 128, DIM / 64), 256, 0, stream>>>(ctx, wob, ob, out);
}